// Round 5
// baseline (741.166 us; speedup 1.0000x reference)
//
#include <hip/hip_runtime.h>

#define NN 50000
#define IN_DIM 128
#define HD 96
#define BN_EPS 1e-5f
#define PN_SCALE 20.0f

// Sanitizer: NaN -> 0, clamp to +-1e15. No-op for sane fp32 data; guarantees
// finite outputs even if the interface dtype is misunderstood (diagnostic aid).
__device__ __forceinline__ float fin(float v) {
    if (!(v == v)) return 0.0f;
    return fminf(fmaxf(v, -1.0e15f), 1.0e15f);
}

__global__ void zero_stats_kernel(float* stats, int n) {
    int i = blockIdx.x * blockDim.x + threadIdx.x;
    if (i < n) stats[i] = 0.0f;
}

// ---------------- GEMM: C[N,96] = act(A[N,K]) @ W[96,K]^T + b ----------------
// MODE 0: A = x [N,128]. Write C to outf (h0 out) AND outf2 (z init).
// MODE 1: A = z [N,96]. Write C (h) to outf. IN-PLACE SAFE (row-local dependency:
//         each block stages its own 8 rows to LDS before overwriting them).
// MODE 2: A = h [N,96], act = relu(a*scale[k]+shift[k]). Write C (l1) in place,
//         plus per-column partial sums -> atomic colsum (PairNorm col mean).
template<int K, int MODE>
__global__ __launch_bounds__(768) void gemm_kernel(
    const float* A, const float* __restrict__ W, const float* __restrict__ bias,
    float* outf, float* outf2,
    const float* __restrict__ scale, const float* __restrict__ shift,
    float* __restrict__ colsum)
{
    __shared__ float As[8 * (K + 1)];
    __shared__ float Ws[HD * (K + 1)];

    const int tid = threadIdx.x;
    const int nl  = tid / HD;      // 0..7 local row
    const int f   = tid % HD;      // 0..95 column
    const size_t base = (size_t)blockIdx.x * 8;

    // stage W, padded leading dim K+1 (odd -> bank-conflict-free)
    for (int idx = tid; idx < HD * K; idx += 768) {
        int r = idx / K, c = idx % K;
        Ws[r * (K + 1) + c] = fin(W[idx]);
    }
    // stage A tile (8 rows)
    if (MODE == 0) {
        for (int idx = tid; idx < 8 * K; idx += 768) {
            int r = idx / K, c = idx % K;
            As[r * (K + 1) + c] = fin(A[(base + r) * K + c]);
        }
    } else {
        float v = fin(A[base * HD + tid]);          // coalesced, row nl col f
        if (MODE == 2) v = fmaxf(v * fin(scale[f]) + fin(shift[f]), 0.0f);
        As[nl * (K + 1) + f] = v;
    }
    __syncthreads();

    float acc = 0.0f;
#pragma unroll 8
    for (int k = 0; k < K; ++k)
        acc += As[nl * (K + 1) + k] * Ws[f * (K + 1) + k];

    float c = fin(acc + fin(bias[f]));
    size_t o = (base + nl) * HD + f;
    outf[o] = c;
    if (MODE == 0) outf2[o] = c;

    if (MODE == 2) {
        __syncthreads();                 // main-loop LDS reads done
        As[nl * (K + 1) + f] = c;        // stash l1 tile
        __syncthreads();
        if (tid < HD) {
            float s = 0.0f;
            for (int r = 0; r < 8; ++r) s += As[r * (K + 1) + tid];
            atomicAdd(&colsum[tid], s);
        }
    }
}

// ---------------- edge scatter: z[dst] += h0[src] ----------------
__global__ void scatter_kernel(const float* __restrict__ h0, const int* __restrict__ ei,
                               float* __restrict__ z, int E)
{
    int idx = blockIdx.x * blockDim.x + threadIdx.x;
    if (idx >= E * HD) return;
    int e = idx / HD;
    int f = idx - e * HD;
    int src = ei[e];
    int dst = ei[E + e];
    if ((unsigned)src >= NN || (unsigned)dst >= NN) return;   // layout guard
    atomicAdd(z + (size_t)dst * HD + f, fin(h0[(size_t)src * HD + f]));
}

// ---------------- BN column stats ----------------
__global__ __launch_bounds__(384) void bn_stats_kernel(const float* __restrict__ h,
                                                       float* __restrict__ sum, float* __restrict__ sumsq)
{
    __shared__ float s1[384];
    __shared__ float s2[384];
    const int tid = threadIdx.x;
    const int f = tid % HD;
    const int rg = tid / HD;   // 0..3
    float a1 = 0.0f, a2 = 0.0f;
    for (int r = blockIdx.x * 4 + rg; r < NN; r += gridDim.x * 4) {
        float v = fin(h[(size_t)r * HD + f]);
        a1 += v; a2 += v * v;
    }
    s1[tid] = a1; s2[tid] = a2;
    __syncthreads();
    if (tid < 192) { s1[tid] += s1[tid + 192]; s2[tid] += s2[tid + 192]; }
    __syncthreads();
    if (tid < HD) {
        atomicAdd(&sum[f],   s1[tid] + s1[tid + HD]);
        atomicAdd(&sumsq[f], s2[tid] + s2[tid + HD]);
    }
}

__global__ void bn_finalize_kernel(const float* __restrict__ sum, const float* __restrict__ sumsq,
                                   const float* __restrict__ gamma, const float* __restrict__ beta,
                                   float* __restrict__ scale, float* __restrict__ shift)
{
    int f = threadIdx.x;
    if (f < HD) {
        float mean = fin(sum[f]) * (1.0f / NN);
        float var  = fmaxf(fin(sumsq[f]) * (1.0f / NN) - mean * mean, 0.0f);
        float rstd = rsqrtf(var + BN_EPS);
        float sc = rstd * fin(gamma[f]);
        scale[f] = fin(sc);
        shift[f] = fin(fin(beta[f]) - mean * sc);
    }
}

// ---------------- PairNorm: one wave (64 threads) per row, in-place ----------------
__global__ __launch_bounds__(64) void pn_kernel(float* l1, const float* __restrict__ colsum)
{
    const int n = blockIdx.x;
    const int t = threadIdx.x;
    float v0 = fin(l1[(size_t)n * HD + t]);
    float v1 = (t < HD - 64) ? fin(l1[(size_t)n * HD + 64 + t]) : 0.0f;
    float ss = v0 * v0 + v1 * v1;
#pragma unroll
    for (int off = 32; off > 0; off >>= 1) ss += __shfl_down(ss, off, 64);
    ss = __shfl(ss, 0, 64);
    float rs = rsqrtf(1e-6f + ss);
    float c0 = fin(colsum[t]) * (1.0f / NN);
    l1[(size_t)n * HD + t] = PN_SCALE * v0 * rs - c0;
    if (t < HD - 64) {
        float c1 = fin(colsum[64 + t]) * (1.0f / NN);
        l1[(size_t)n * HD + 64 + t] = PN_SCALE * v1 * rs - c1;
    }
}

extern "C" void kernel_launch(void* const* d_in, const int* in_sizes, int n_in,
                              void* d_out, int out_size, void* d_ws, size_t ws_size,
                              hipStream_t stream) {
    const float* x     = (const float*)d_in[0];
    const int*   ei    = (const int*)d_in[1];
    const float* W0    = (const float*)d_in[2];
    const float* b0    = (const float*)d_in[3];
    const float* W1    = (const float*)d_in[4];
    const float* b1    = (const float*)d_in[5];
    const float* gamma = (const float*)d_in[6];
    const float* beta  = (const float*)d_in[7];
    const float* W2    = (const float*)d_in[8];
    const float* b2    = (const float*)d_in[9];

    float* out_l1 = (float*)d_out;                 // [N,96]: z -> h -> l1 (in place)
    float* out_h0 = out_l1 + (size_t)NN * HD;      // [N,96]: h0 output

    // ws: 480 floats only (1920 B)
    float* stats   = (float*)d_ws;
    float* s_sum   = stats;
    float* s_sumsq = stats + HD;
    float* s_col   = stats + 2 * HD;
    float* s_scale = stats + 3 * HD;
    float* s_shift = stats + 4 * HD;

    const int E = in_sizes[1] / 2;                 // 800000

    // 0) zero stats accumulators
    zero_stats_kernel<<<1, 512, 0, stream>>>(stats, 5 * HD);
    // 1) h0 = x @ W0^T + b0 -> out_h0 (output) and out_l1 (z init)
    gemm_kernel<IN_DIM, 0><<<NN / 8, 768, 0, stream>>>(x, W0, b0, out_h0, out_l1,
                                                       nullptr, nullptr, nullptr);
    // 2) z[dst] += h0[src] over edges
    {
        int total = E * HD;
        scatter_kernel<<<(total + 255) / 256, 256, 0, stream>>>(out_h0, ei, out_l1, E);
    }
    // 3) h = z @ W1^T + b1 (in place on out_l1)
    gemm_kernel<HD, 1><<<NN / 8, 768, 0, stream>>>(out_l1, W1, b1, out_l1, nullptr,
                                                   nullptr, nullptr, nullptr);
    // 4) BN stats + finalize
    bn_stats_kernel<<<128, 384, 0, stream>>>(out_l1, s_sum, s_sumsq);
    bn_finalize_kernel<<<1, 128, 0, stream>>>(s_sum, s_sumsq, gamma, beta, s_scale, s_shift);
    // 5) l1 = relu(bn(h)) @ W2^T + b2 (in place) + column sums
    gemm_kernel<HD, 2><<<NN / 8, 768, 0, stream>>>(out_l1, W2, b2, out_l1, nullptr,
                                                   s_scale, s_shift, s_col);
    // 6) PairNorm (one wave per row, in place)
    pn_kernel<<<NN, 64, 0, stream>>>(out_l1, s_col);
}

// Round 6
// 580.792 us; speedup vs baseline: 1.2761x; 1.2761x over previous
//
#include <hip/hip_runtime.h>

#define NN 50000
#define IN_DIM 128
#define HD 96
#define BN_EPS 1e-5f
#define PN_SCALE 20.0f

// ---------------- zero stats + CSR counters ----------------
__global__ void zero_kernel(float* stats, int* cnt) {
    int i = blockIdx.x * blockDim.x + threadIdx.x;
    if (i < 1024) stats[i] = 0.0f;
    int j = i - 1024;
    if (j >= 0 && j < NN) cnt[j] = 0;
}

// ---------------- tiled GEMM: C[N,96] = act(A[N,K]) @ W[96,K]^T + b ----------
// 64-row x 96-col block tile, 256 threads, 4x6 per thread, K chunked by 32.
// MODE 0: plain (gemm1: x -> h0)
// MODE 1: plain, in-place safe (gemm2: z -> h; reads of own rows all precede stores)
// MODE 2: A-activation relu(a*scale[k]+shift[k]) (gemm3: h -> l1, in place)
template<int K, int MODE>
__global__ __launch_bounds__(256) void gemm_tiled(
    const float* A, const float* __restrict__ W, const float* __restrict__ bias,
    float* out, const float* __restrict__ scale, const float* __restrict__ shift)
{
    constexpr int CK = 32;
    __shared__ float As[64 * (CK + 1)];
    __shared__ float Ws[HD * (CK + 1)];

    const int t  = threadIdx.x;
    const int tx = t & 15;        // col group: cols tx*6 .. tx*6+5
    const int ty = t >> 4;        // row group: rows ty*4 .. ty*4+3
    const int base = blockIdx.x * 64;

    float acc[4][6];
#pragma unroll
    for (int i = 0; i < 4; ++i)
#pragma unroll
        for (int j = 0; j < 6; ++j) acc[i][j] = 0.0f;

    for (int kc = 0; kc < K; kc += CK) {
        // stage A: 64x32 = 512 float4
#pragma unroll
        for (int it = 0; it < 2; ++it) {
            int q = t + it * 256;
            int r = q >> 3, c4 = q & 7;
            int row = base + r;
            float4 v = make_float4(0.f, 0.f, 0.f, 0.f);
            if (row < NN) v = *(const float4*)(A + (size_t)row * K + kc + c4 * 4);
            if (MODE == 2) {
                float4 sc = *(const float4*)(scale + kc + c4 * 4);
                float4 sh = *(const float4*)(shift + kc + c4 * 4);
                v.x = fmaxf(v.x * sc.x + sh.x, 0.f);
                v.y = fmaxf(v.y * sc.y + sh.y, 0.f);
                v.z = fmaxf(v.z * sc.z + sh.z, 0.f);
                v.w = fmaxf(v.w * sc.w + sh.w, 0.f);
            }
            float* d = As + r * (CK + 1) + c4 * 4;
            d[0] = v.x; d[1] = v.y; d[2] = v.z; d[3] = v.w;
        }
        // stage W: 96x32 = 768 float4
#pragma unroll
        for (int it = 0; it < 3; ++it) {
            int q = t + it * 256;
            int r = q >> 3, c4 = q & 7;
            float4 v = *(const float4*)(W + (size_t)r * K + kc + c4 * 4);
            float* d = Ws + r * (CK + 1) + c4 * 4;
            d[0] = v.x; d[1] = v.y; d[2] = v.z; d[3] = v.w;
        }
        __syncthreads();
#pragma unroll
        for (int kk = 0; kk < CK; ++kk) {
            float a[4], b[6];
#pragma unroll
            for (int i = 0; i < 4; ++i) a[i] = As[(ty * 4 + i) * (CK + 1) + kk];
#pragma unroll
            for (int j = 0; j < 6; ++j) b[j] = Ws[(tx * 6 + j) * (CK + 1) + kk];
#pragma unroll
            for (int i = 0; i < 4; ++i)
#pragma unroll
                for (int j = 0; j < 6; ++j) acc[i][j] += a[i] * b[j];
        }
        __syncthreads();
    }

    float bs[6];
#pragma unroll
    for (int j = 0; j < 6; ++j) bs[j] = bias[tx * 6 + j];
#pragma unroll
    for (int i = 0; i < 4; ++i) {
        int row = base + ty * 4 + i;
        if (row < NN) {
#pragma unroll
            for (int j = 0; j < 6; ++j)
                out[(size_t)row * HD + tx * 6 + j] = acc[i][j] + bs[j];
        }
    }
}

// ---------------- CSR build ----------------
__global__ void hist_kernel(const int* __restrict__ ei, int* __restrict__ cnt, int E) {
    int e = blockIdx.x * blockDim.x + threadIdx.x;
    if (e < E) atomicAdd(&cnt[ei[E + e]], 1);
}

__global__ __launch_bounds__(1024) void scan_kernel(int* cnt, int* rowptr) {
    __shared__ int part[1024];
    const int CH = (NN + 1023) / 1024;  // 49
    const int t = threadIdx.x;
    const int begin = t * CH;
    const int end = min(begin + CH, NN);
    int s = 0;
    for (int i = begin; i < end; ++i) s += cnt[i];
    part[t] = s;
    __syncthreads();
    for (int off = 1; off < 1024; off <<= 1) {
        int v = part[t];
        if (t >= off) v += part[t - off];
        __syncthreads();
        part[t] = v;
        __syncthreads();
    }
    int run = (t == 0) ? 0 : part[t - 1];
    for (int i = begin; i < end; ++i) {
        int c = cnt[i];
        rowptr[i] = run;
        cnt[i] = run;          // becomes the fill cursor
        run += c;
    }
    if (begin < NN && end == NN) rowptr[NN] = run;
}

__global__ void fill_kernel(const int* __restrict__ ei, int* __restrict__ cursor,
                            int* __restrict__ srcs, int E) {
    int e = blockIdx.x * blockDim.x + threadIdx.x;
    if (e >= E) return;
    int src = ei[e];
    int dst = ei[E + e];
    int slot = atomicAdd(&cursor[dst], 1);
    srcs[slot] = src;
}

// ---------------- gather: z[i] = h0[i] + sum_{e:dst=i} h0[src_e] ----------------
__global__ __launch_bounds__(768) void gather_kernel(
    const float* __restrict__ h0, const int* __restrict__ rowptr,
    const int* __restrict__ srcs, float* __restrict__ z)
{
    const int tid = threadIdx.x;
    const int nl = tid / HD;
    const int f = tid - nl * HD;
    const int row = blockIdx.x * 8 + nl;
    int p0 = rowptr[row], p1 = rowptr[row + 1];
    float s = h0[(size_t)row * HD + f];
    for (int p = p0; p < p1; ++p) {
        int sr = srcs[p];
        s += h0[(size_t)sr * HD + f];
    }
    z[(size_t)row * HD + f] = s;
}

// ---------------- column stats (sum + sumsq) ----------------
__global__ __launch_bounds__(384) void col_stats_kernel(const float* __restrict__ h,
                                                        float* __restrict__ sum,
                                                        float* __restrict__ sumsq)
{
    __shared__ float s1[384];
    __shared__ float s2[384];
    const int tid = threadIdx.x;
    const int f = tid % HD;
    const int rg = tid / HD;   // 0..3
    float a1 = 0.0f, a2 = 0.0f;
    for (int r = blockIdx.x * 4 + rg; r < NN; r += gridDim.x * 4) {
        float v = h[(size_t)r * HD + f];
        a1 += v; a2 += v * v;
    }
    s1[tid] = a1; s2[tid] = a2;
    __syncthreads();
    if (tid < 192) { s1[tid] += s1[tid + 192]; s2[tid] += s2[tid + 192]; }
    __syncthreads();
    if (tid < HD) {
        atomicAdd(&sum[f],   s1[tid] + s1[tid + HD]);
        atomicAdd(&sumsq[f], s2[tid] + s2[tid + HD]);
    }
}

__global__ void bn_finalize_kernel(const float* __restrict__ sum, const float* __restrict__ sumsq,
                                   const float* __restrict__ gamma, const float* __restrict__ beta,
                                   float* __restrict__ scale, float* __restrict__ shift)
{
    int f = threadIdx.x;
    if (f < HD) {
        float mean = sum[f] * (1.0f / NN);
        float var  = fmaxf(sumsq[f] * (1.0f / NN) - mean * mean, 0.0f);
        float rstd = rsqrtf(var + BN_EPS);
        float sc = rstd * gamma[f];
        scale[f] = sc;
        shift[f] = beta[f] - mean * sc;
    }
}

// ---------------- PairNorm: one wave per row, in-place ----------------
__global__ __launch_bounds__(64) void pn_kernel(float* l1, const float* __restrict__ colsum)
{
    const int n = blockIdx.x;
    const int t = threadIdx.x;
    float v0 = l1[(size_t)n * HD + t];
    float v1 = (t < HD - 64) ? l1[(size_t)n * HD + 64 + t] : 0.0f;
    float ss = v0 * v0 + v1 * v1;
#pragma unroll
    for (int off = 32; off > 0; off >>= 1) ss += __shfl_down(ss, off, 64);
    ss = __shfl(ss, 0, 64);
    float rs = rsqrtf(1e-6f + ss);
    l1[(size_t)n * HD + t] = PN_SCALE * v0 * rs - colsum[t] * (1.0f / NN);
    if (t < HD - 64)
        l1[(size_t)n * HD + 64 + t] = PN_SCALE * v1 * rs - colsum[64 + t] * (1.0f / NN);
}

extern "C" void kernel_launch(void* const* d_in, const int* in_sizes, int n_in,
                              void* d_out, int out_size, void* d_ws, size_t ws_size,
                              hipStream_t stream) {
    const float* x     = (const float*)d_in[0];
    const int*   ei    = (const int*)d_in[1];
    const float* W0    = (const float*)d_in[2];
    const float* b0    = (const float*)d_in[3];
    const float* W1    = (const float*)d_in[4];
    const float* b1    = (const float*)d_in[5];
    const float* gamma = (const float*)d_in[6];
    const float* beta  = (const float*)d_in[7];
    const float* W2    = (const float*)d_in[8];
    const float* b2    = (const float*)d_in[9];

    float* out_l1 = (float*)d_out;                 // [N,96]: z -> h -> l1 (in place)
    float* out_h0 = out_l1 + (size_t)NN * HD;      // [N,96]: h0 output

    // ws layout (~3.6 MB):
    //   stats: 1024 floats  [sum|sumsq|col|coldummy|scale|shift]
    //   cnt/cursor: NN ints; rowptr: NN+1 ints; srcs: E ints
    float* stats   = (float*)d_ws;
    float* s_sum   = stats;
    float* s_sumsq = stats + HD;
    float* s_col   = stats + 2 * HD;
    float* s_cold  = stats + 3 * HD;
    float* s_scale = stats + 4 * HD;
    float* s_shift = stats + 5 * HD;
    int* cnt    = (int*)(stats + 1024);
    int* rowptr = cnt + NN;
    int* srcs   = rowptr + NN + 2;

    const int E = in_sizes[1] / 2;                 // 800000
    const int GB = (NN + 63) / 64;                 // 782 gemm blocks

    // 0) zero stats + histogram counters
    zero_kernel<<<(1024 + NN + 255) / 256, 256, 0, stream>>>(stats, cnt);
    // 1) h0 = x @ W0^T + b0 -> out_h0
    gemm_tiled<IN_DIM, 0><<<GB, 256, 0, stream>>>(x, W0, b0, out_h0, nullptr, nullptr);
    // 2) CSR build: histogram -> scan -> fill
    hist_kernel<<<(E + 255) / 256, 256, 0, stream>>>(ei, cnt, E);
    scan_kernel<<<1, 1024, 0, stream>>>(cnt, rowptr);
    fill_kernel<<<(E + 255) / 256, 256, 0, stream>>>(ei, cnt, srcs, E);
    // 3) gather: z = h0 + segment_sum(h0[src]) -> out_l1
    gather_kernel<<<NN / 8, 768, 0, stream>>>(out_h0, rowptr, srcs, out_l1);
    // 4) h = z @ W1^T + b1 (in place)
    gemm_tiled<HD, 1><<<GB, 256, 0, stream>>>(out_l1, W1, b1, out_l1, nullptr, nullptr);
    // 5) BN stats + finalize
    col_stats_kernel<<<128, 384, 0, stream>>>(out_l1, s_sum, s_sumsq);
    bn_finalize_kernel<<<1, 128, 0, stream>>>(s_sum, s_sumsq, gamma, beta, s_scale, s_shift);
    // 6) l1 = relu(bn(h)) @ W2^T + b2 (in place)
    gemm_tiled<HD, 2><<<GB, 256, 0, stream>>>(out_l1, W2, b2, out_l1, s_scale, s_shift);
    // 7) PairNorm column sums (sumsq slot is a dummy), then finalize in place
    col_stats_kernel<<<128, 384, 0, stream>>>(out_l1, s_col, s_cold);
    pn_kernel<<<NN, 64, 0, stream>>>(out_l1, s_col);
}

// Round 7
// 455.359 us; speedup vs baseline: 1.6277x; 1.2755x over previous
//
#include <hip/hip_runtime.h>

#define NN 50000
#define IN_DIM 128
#define HD 96
#define BN_EPS 1e-5f
#define PN_SCALE 20.0f

__device__ __forceinline__ float4 ld4(const float* p) { return *(const float4*)p; }
__device__ __forceinline__ float4 add4(float4 a, float4 b) {
    return make_float4(a.x + b.x, a.y + b.y, a.z + b.z, a.w + b.w);
}

// ---------------- zero stats + CSR counters ----------------
__global__ void zero_kernel(float* stats, int* cnt) {
    int i = blockIdx.x * blockDim.x + threadIdx.x;
    if (i < 1024) stats[i] = 0.0f;
    int j = i - 1024;
    if (j >= 0 && j < NN) cnt[j] = 0;
}

// ---------------- tiled GEMM: C[N,96] = act(A[N,K]) @ W[96,K]^T + b ----------
// 64x96 block tile, 256 threads, 4x6 per thread, K chunked by 32.
// MODE 0: plain (x -> h0)
// MODE 1: in-place (z -> h) + fused BN column sum/sumsq (atomic partials)
// MODE 2: in-place (h -> l1) with relu(a*scale+shift) on A, + fused PairNorm
//         column sums (atomic partials) and per-row sum-of-squares.
template<int K, int MODE>
__global__ __launch_bounds__(256) void gemm_tiled(
    const float* A, const float* __restrict__ W, const float* __restrict__ bias,
    float* out, const float* __restrict__ scale, const float* __restrict__ shift,
    float* __restrict__ gsum, float* __restrict__ gsumsq,
    float* __restrict__ gcol, float* __restrict__ growss)
{
    constexpr int CK = 32;
    __shared__ float sh[64 * (CK + 1) + HD * (CK + 1)];   // 5280 floats
    float* As = sh;
    float* Ws = sh + 64 * (CK + 1);

    const int t  = threadIdx.x;
    const int tx = t & 15;        // col group: cols tx*6 .. tx*6+5
    const int ty = t >> 4;        // row group: rows ty*4 .. ty*4+3
    const int base = blockIdx.x * 64;

    float acc[4][6];
#pragma unroll
    for (int i = 0; i < 4; ++i)
#pragma unroll
        for (int j = 0; j < 6; ++j) acc[i][j] = 0.0f;

    for (int kc = 0; kc < K; kc += CK) {
#pragma unroll
        for (int it = 0; it < 2; ++it) {
            int q = t + it * 256;
            int r = q >> 3, c4 = q & 7;
            int row = base + r;
            float4 v = make_float4(0.f, 0.f, 0.f, 0.f);
            if (row < NN) v = ld4(A + (size_t)row * K + kc + c4 * 4);
            if (MODE == 2) {
                float4 sc = ld4(scale + kc + c4 * 4);
                float4 shf = ld4(shift + kc + c4 * 4);
                v.x = fmaxf(v.x * sc.x + shf.x, 0.f);
                v.y = fmaxf(v.y * sc.y + shf.y, 0.f);
                v.z = fmaxf(v.z * sc.z + shf.z, 0.f);
                v.w = fmaxf(v.w * sc.w + shf.w, 0.f);
            }
            float* d = As + r * (CK + 1) + c4 * 4;
            d[0] = v.x; d[1] = v.y; d[2] = v.z; d[3] = v.w;
        }
#pragma unroll
        for (int it = 0; it < 3; ++it) {
            int q = t + it * 256;
            int r = q >> 3, c4 = q & 7;
            float4 v = ld4(W + (size_t)r * K + kc + c4 * 4);
            float* d = Ws + r * (CK + 1) + c4 * 4;
            d[0] = v.x; d[1] = v.y; d[2] = v.z; d[3] = v.w;
        }
        __syncthreads();
#pragma unroll
        for (int kk = 0; kk < CK; ++kk) {
            float a[4], b[6];
#pragma unroll
            for (int i = 0; i < 4; ++i) a[i] = As[(ty * 4 + i) * (CK + 1) + kk];
#pragma unroll
            for (int j = 0; j < 6; ++j) b[j] = Ws[(tx * 6 + j) * (CK + 1) + kk];
#pragma unroll
            for (int i = 0; i < 4; ++i)
#pragma unroll
                for (int j = 0; j < 6; ++j) acc[i][j] += a[i] * b[j];
        }
        __syncthreads();
    }

    float cv[4][6];
#pragma unroll
    for (int j = 0; j < 6; ++j) {
        float bs = bias[tx * 6 + j];
#pragma unroll
        for (int i = 0; i < 4; ++i) cv[i][j] = acc[i][j] + bs;
    }
#pragma unroll
    for (int i = 0; i < 4; ++i) {
        int row = base + ty * 4 + i;
        if (row < NN) {
#pragma unroll
            for (int j = 0; j < 6; ++j)
                out[(size_t)row * HD + tx * 6 + j] = cv[i][j];
        }
    }

    if (MODE == 1) {
        // fused BN stats: partial col sum + sumsq (masked tail rows)
        float* rs_sum = sh;            // [16][96]
        float* rs_sq  = sh + 1536;     // [16][96]
        // last barrier of k-loop already passed; LDS reusable after one more sync
        __syncthreads();
#pragma unroll
        for (int j = 0; j < 6; ++j) {
            float s = 0.f, q = 0.f;
#pragma unroll
            for (int i = 0; i < 4; ++i) {
                int row = base + ty * 4 + i;
                float v = (row < NN) ? cv[i][j] : 0.f;
                s += v; q += v * v;
            }
            rs_sum[ty * HD + tx * 6 + j] = s;
            rs_sq[ty * HD + tx * 6 + j]  = q;
        }
        __syncthreads();
        if (t < HD) {
            float S = 0.f, Q = 0.f;
#pragma unroll
            for (int r = 0; r < 16; ++r) { S += rs_sum[r * HD + t]; Q += rs_sq[r * HD + t]; }
            atomicAdd(&gsum[t], S);
            atomicAdd(&gsumsq[t], Q);
        }
    }

    if (MODE == 2) {
        // fused PairNorm stats: partial col sums + per-row sumsq
        float* rs_sum = sh;            // [16][96]
        float* rr     = sh + 1536;     // [64][16]
        __syncthreads();
#pragma unroll
        for (int j = 0; j < 6; ++j) {
            float s = 0.f;
#pragma unroll
            for (int i = 0; i < 4; ++i) {
                int row = base + ty * 4 + i;
                s += (row < NN) ? cv[i][j] : 0.f;
            }
            rs_sum[ty * HD + tx * 6 + j] = s;
        }
#pragma unroll
        for (int i = 0; i < 4; ++i) {
            float q = 0.f;
#pragma unroll
            for (int j = 0; j < 6; ++j) q += cv[i][j] * cv[i][j];
            rr[(ty * 4 + i) * 16 + tx] = q;
        }
        __syncthreads();
        if (t < HD) {
            float S = 0.f;
#pragma unroll
            for (int r = 0; r < 16; ++r) S += rs_sum[r * HD + t];
            atomicAdd(&gcol[t], S);
        }
        if (t < 64) {
            int row = base + t;
            if (row < NN) {
                float S = 0.f;
#pragma unroll
                for (int g = 0; g < 16; ++g) S += rr[t * 16 + g];
                growss[row] = S;
            }
        }
    }
}

// ---------------- CSR build ----------------
__global__ void hist_kernel(const int* __restrict__ ei, int* __restrict__ cnt, int E) {
    int e = blockIdx.x * blockDim.x + threadIdx.x;
    if (e < E) atomicAdd(&cnt[ei[E + e]], 1);
}

__global__ __launch_bounds__(1024) void scan_kernel(int* cnt, int* rowptr) {
    __shared__ int part[1024];
    const int CH = (NN + 1023) / 1024;  // 49
    const int t = threadIdx.x;
    const int begin = t * CH;
    const int end = min(begin + CH, NN);
    int s = 0;
    for (int i = begin; i < end; ++i) s += cnt[i];
    part[t] = s;
    __syncthreads();
    for (int off = 1; off < 1024; off <<= 1) {
        int v = part[t];
        if (t >= off) v += part[t - off];
        __syncthreads();
        part[t] = v;
        __syncthreads();
    }
    int run = (t == 0) ? 0 : part[t - 1];
    for (int i = begin; i < end; ++i) {
        int c = cnt[i];
        rowptr[i] = run;
        cnt[i] = run;          // becomes the fill cursor
        run += c;
    }
    if (begin < NN && end == NN) rowptr[NN] = run;
}

__global__ void fill_kernel(const int* __restrict__ ei, int* __restrict__ cursor,
                            int* __restrict__ srcs, int E) {
    int e = blockIdx.x * blockDim.x + threadIdx.x;
    if (e >= E) return;
    int src = ei[e];
    int dst = ei[E + e];
    int slot = atomicAdd(&cursor[dst], 1);
    srcs[slot] = src;
}

// -------- gather: z[i] = h0[i] + sum_{e:dst=i} h0[src_e]  (float4, 4-way split) ----
// 8 rows/block; per row 96 threads = 4 edge-groups x 24 float4-lanes.
__global__ __launch_bounds__(768) void gather_kernel(
    const float* __restrict__ h0, const int* __restrict__ rowptr,
    const int* __restrict__ srcs, float* __restrict__ z)
{
    __shared__ float4 red[768];
    const int tid = threadIdx.x;
    const int rl  = tid / 96;          // 0..7
    const int wi  = tid - rl * 96;
    const int g   = wi / 24;           // 0..3 edge group
    const int c   = wi - g * 24;       // 0..23 float4 lane
    const int row = blockIdx.x * 8 + rl;

    const int p0 = rowptr[row];
    const int cnt = rowptr[row + 1] - p0;
    int q0 = p0 + (cnt * g) / 4;
    int q1 = p0 + (cnt * (g + 1)) / 4;

    float4 acc = (g == 0) ? ld4(h0 + (size_t)row * HD + c * 4)
                          : make_float4(0.f, 0.f, 0.f, 0.f);
    int p = q0;
    for (; p + 4 <= q1; p += 4) {
        int s0 = srcs[p], s1 = srcs[p + 1], s2 = srcs[p + 2], s3 = srcs[p + 3];
        float4 v0 = ld4(h0 + (size_t)s0 * HD + c * 4);
        float4 v1 = ld4(h0 + (size_t)s1 * HD + c * 4);
        float4 v2 = ld4(h0 + (size_t)s2 * HD + c * 4);
        float4 v3 = ld4(h0 + (size_t)s3 * HD + c * 4);
        acc = add4(acc, add4(add4(v0, v1), add4(v2, v3)));
    }
    for (; p < q1; ++p)
        acc = add4(acc, ld4(h0 + (size_t)srcs[p] * HD + c * 4));

    red[tid] = acc;
    __syncthreads();
    if (g == 0) {
        acc = add4(add4(acc, red[tid + 24]), add4(red[tid + 48], red[tid + 72]));
        *(float4*)(z + (size_t)row * HD + c * 4) = acc;
    }
}

__global__ void bn_finalize_kernel(const float* __restrict__ sum, const float* __restrict__ sumsq,
                                   const float* __restrict__ gamma, const float* __restrict__ beta,
                                   float* __restrict__ scale, float* __restrict__ shift)
{
    int f = threadIdx.x;
    if (f < HD) {
        float mean = sum[f] * (1.0f / NN);
        float var  = fmaxf(sumsq[f] * (1.0f / NN) - mean * mean, 0.0f);
        float rstd = rsqrtf(var + BN_EPS);
        float sc = rstd * gamma[f];
        scale[f] = sc;
        shift[f] = beta[f] - mean * sc;
    }
}

// ---------------- PairNorm: streaming float4, in place ----------------
__global__ __launch_bounds__(256) void pn_kernel(float* l1, const float* __restrict__ colsum,
                                                 const float* __restrict__ rowss)
{
    int idx = blockIdx.x * 256 + threadIdx.x;   // float4 index
    if (idx >= NN * 24) return;
    int row = idx / 24;
    int q = idx - row * 24;
    float rs = rsqrtf(1e-6f + rowss[row]);
    float4 v = ld4(l1 + (size_t)idx * 4);
    float4 cm = ld4(colsum + q * 4);
    v.x = PN_SCALE * v.x * rs - cm.x * (1.0f / NN);
    v.y = PN_SCALE * v.y * rs - cm.y * (1.0f / NN);
    v.z = PN_SCALE * v.z * rs - cm.z * (1.0f / NN);
    v.w = PN_SCALE * v.w * rs - cm.w * (1.0f / NN);
    *(float4*)(l1 + (size_t)idx * 4) = v;
}

extern "C" void kernel_launch(void* const* d_in, const int* in_sizes, int n_in,
                              void* d_out, int out_size, void* d_ws, size_t ws_size,
                              hipStream_t stream) {
    const float* x     = (const float*)d_in[0];
    const int*   ei    = (const int*)d_in[1];
    const float* W0    = (const float*)d_in[2];
    const float* b0    = (const float*)d_in[3];
    const float* W1    = (const float*)d_in[4];
    const float* b1    = (const float*)d_in[5];
    const float* gamma = (const float*)d_in[6];
    const float* beta  = (const float*)d_in[7];
    const float* W2    = (const float*)d_in[8];
    const float* b2    = (const float*)d_in[9];

    float* out_l1 = (float*)d_out;                 // [N,96]: z -> h -> l1 (in place)
    float* out_h0 = out_l1 + (size_t)NN * HD;      // [N,96]: h0 output

    // ws (~3.8 MB): stats 1024 fl | rowss NN fl | cnt NN int | rowptr NN+2 int | srcs E int
    float* stats   = (float*)d_ws;
    float* s_sum   = stats;            // 96
    float* s_sumsq = stats + HD;       // 96
    float* s_col   = stats + 2 * HD;   // 96 (float4-aligned: 768 B)
    float* s_scale = stats + 288;      // 96 (1152 B aligned)
    float* s_shift = stats + 384;      // 96 (1536 B aligned)
    float* rowss = stats + 1024;
    int* cnt    = (int*)(rowss + NN);
    int* rowptr = cnt + NN;
    int* srcs   = rowptr + NN + 2;

    const int E = in_sizes[1] / 2;                 // 800000
    const int GB = (NN + 63) / 64;                 // 782

    zero_kernel<<<(1024 + NN + 255) / 256, 256, 0, stream>>>(stats, cnt);
    // 1) h0 = x @ W0^T + b0
    gemm_tiled<IN_DIM, 0><<<GB, 256, 0, stream>>>(x, W0, b0, out_h0, nullptr, nullptr,
                                                  nullptr, nullptr, nullptr, nullptr);
    // 2) CSR build
    hist_kernel<<<(E + 255) / 256, 256, 0, stream>>>(ei, cnt, E);
    scan_kernel<<<1, 1024, 0, stream>>>(cnt, rowptr);
    fill_kernel<<<(E + 255) / 256, 256, 0, stream>>>(ei, cnt, srcs, E);
    // 3) gather: z = h0 + segment_sum(h0[src])
    gather_kernel<<<NN / 8, 768, 0, stream>>>(out_h0, rowptr, srcs, out_l1);
    // 4) h = z @ W1^T + b1 (in place) + fused BN stats
    gemm_tiled<HD, 1><<<GB, 256, 0, stream>>>(out_l1, W1, b1, out_l1, nullptr, nullptr,
                                              s_sum, s_sumsq, nullptr, nullptr);
    bn_finalize_kernel<<<1, 128, 0, stream>>>(s_sum, s_sumsq, gamma, beta, s_scale, s_shift);
    // 5) l1 = relu(bn(h)) @ W2^T + b2 (in place) + fused PN stats
    gemm_tiled<HD, 2><<<GB, 256, 0, stream>>>(out_l1, W2, b2, out_l1, s_scale, s_shift,
                                              nullptr, nullptr, s_col, rowss);
    // 6) PairNorm finalize (streaming, in place)
    pn_kernel<<<(NN * 24 + 255) / 256, 256, 0, stream>>>(out_l1, s_col, rowss);
}

// Round 8
// 360.665 us; speedup vs baseline: 2.0550x; 1.2626x over previous
//
#include <hip/hip_runtime.h>

#define NN 50000
#define IN_DIM 128
#define HD 96
#define BN_EPS 1e-5f
#define PN_SCALE 20.0f
#define SCAN_NB 196   // ceil(50000/256)

__device__ __forceinline__ float4 ld4(const float* p) { return *(const float4*)p; }
__device__ __forceinline__ float4 add4(float4 a, float4 b) {
    return make_float4(a.x + b.x, a.y + b.y, a.z + b.z, a.w + b.w);
}

// ---------------- zero stats + CSR counters ----------------
__global__ void zero_kernel(float* stats, int* cnt) {
    int i = blockIdx.x * blockDim.x + threadIdx.x;
    if (i < 1024) stats[i] = 0.0f;
    int j = i - 1024;
    if (j >= 0 && j < NN) cnt[j] = 0;
}

// ---------------- tiled GEMM: C[N,96] = act(A[N,K]) @ W[96,K]^T + b ----------
// 64x96 block tile, 256 threads, 4x6 per thread, K chunked by 32.
// MODE 0: plain (x -> h0)
// MODE 1: in-place (z -> h) + fused BN column sum/sumsq (atomic partials)
// MODE 2: in-place (h -> l1) with relu(a*scale+shift) on A, + fused PairNorm
//         column sums (atomic partials) and per-row sum-of-squares.
template<int K, int MODE>
__global__ __launch_bounds__(256) void gemm_tiled(
    const float* A, const float* __restrict__ W, const float* __restrict__ bias,
    float* out, const float* __restrict__ scale, const float* __restrict__ shift,
    float* __restrict__ gsum, float* __restrict__ gsumsq,
    float* __restrict__ gcol, float* __restrict__ growss)
{
    constexpr int CK = 32;
    __shared__ float sh[64 * (CK + 1) + HD * (CK + 1)];   // 5280 floats
    float* As = sh;
    float* Ws = sh + 64 * (CK + 1);

    const int t  = threadIdx.x;
    const int tx = t & 15;        // col group: cols tx*6 .. tx*6+5
    const int ty = t >> 4;        // row group: rows ty*4 .. ty*4+3
    const int base = blockIdx.x * 64;

    float acc[4][6];
#pragma unroll
    for (int i = 0; i < 4; ++i)
#pragma unroll
        for (int j = 0; j < 6; ++j) acc[i][j] = 0.0f;

    for (int kc = 0; kc < K; kc += CK) {
#pragma unroll
        for (int it = 0; it < 2; ++it) {
            int q = t + it * 256;
            int r = q >> 3, c4 = q & 7;
            int row = base + r;
            float4 v = make_float4(0.f, 0.f, 0.f, 0.f);
            if (row < NN) v = ld4(A + (size_t)row * K + kc + c4 * 4);
            if (MODE == 2) {
                float4 sc = ld4(scale + kc + c4 * 4);
                float4 shf = ld4(shift + kc + c4 * 4);
                v.x = fmaxf(v.x * sc.x + shf.x, 0.f);
                v.y = fmaxf(v.y * sc.y + shf.y, 0.f);
                v.z = fmaxf(v.z * sc.z + shf.z, 0.f);
                v.w = fmaxf(v.w * sc.w + shf.w, 0.f);
            }
            float* d = As + r * (CK + 1) + c4 * 4;
            d[0] = v.x; d[1] = v.y; d[2] = v.z; d[3] = v.w;
        }
#pragma unroll
        for (int it = 0; it < 3; ++it) {
            int q = t + it * 256;
            int r = q >> 3, c4 = q & 7;
            float4 v = ld4(W + (size_t)r * K + kc + c4 * 4);
            float* d = Ws + r * (CK + 1) + c4 * 4;
            d[0] = v.x; d[1] = v.y; d[2] = v.z; d[3] = v.w;
        }
        __syncthreads();
#pragma unroll
        for (int kk = 0; kk < CK; ++kk) {
            float a[4], b[6];
#pragma unroll
            for (int i = 0; i < 4; ++i) a[i] = As[(ty * 4 + i) * (CK + 1) + kk];
#pragma unroll
            for (int j = 0; j < 6; ++j) b[j] = Ws[(tx * 6 + j) * (CK + 1) + kk];
#pragma unroll
            for (int i = 0; i < 4; ++i)
#pragma unroll
                for (int j = 0; j < 6; ++j) acc[i][j] += a[i] * b[j];
        }
        __syncthreads();
    }

    float cv[4][6];
#pragma unroll
    for (int j = 0; j < 6; ++j) {
        float bs = bias[tx * 6 + j];
#pragma unroll
        for (int i = 0; i < 4; ++i) cv[i][j] = acc[i][j] + bs;
    }
#pragma unroll
    for (int i = 0; i < 4; ++i) {
        int row = base + ty * 4 + i;
        if (row < NN) {
#pragma unroll
            for (int j = 0; j < 6; ++j)
                out[(size_t)row * HD + tx * 6 + j] = cv[i][j];
        }
    }

    if (MODE == 1) {
        float* rs_sum = sh;            // [16][96]
        float* rs_sq  = sh + 1536;     // [16][96]
        __syncthreads();
#pragma unroll
        for (int j = 0; j < 6; ++j) {
            float s = 0.f, q = 0.f;
#pragma unroll
            for (int i = 0; i < 4; ++i) {
                int row = base + ty * 4 + i;
                float v = (row < NN) ? cv[i][j] : 0.f;
                s += v; q += v * v;
            }
            rs_sum[ty * HD + tx * 6 + j] = s;
            rs_sq[ty * HD + tx * 6 + j]  = q;
        }
        __syncthreads();
        if (t < HD) {
            float S = 0.f, Q = 0.f;
#pragma unroll
            for (int r = 0; r < 16; ++r) { S += rs_sum[r * HD + t]; Q += rs_sq[r * HD + t]; }
            atomicAdd(&gsum[t], S);
            atomicAdd(&gsumsq[t], Q);
        }
    }

    if (MODE == 2) {
        float* rs_sum = sh;            // [16][96]
        float* rr     = sh + 1536;     // [64][16]
        __syncthreads();
#pragma unroll
        for (int j = 0; j < 6; ++j) {
            float s = 0.f;
#pragma unroll
            for (int i = 0; i < 4; ++i) {
                int row = base + ty * 4 + i;
                s += (row < NN) ? cv[i][j] : 0.f;
            }
            rs_sum[ty * HD + tx * 6 + j] = s;
        }
#pragma unroll
        for (int i = 0; i < 4; ++i) {
            float q = 0.f;
#pragma unroll
            for (int j = 0; j < 6; ++j) q += cv[i][j] * cv[i][j];
            rr[(ty * 4 + i) * 16 + tx] = q;
        }
        __syncthreads();
        if (t < HD) {
            float S = 0.f;
#pragma unroll
            for (int r = 0; r < 16; ++r) S += rs_sum[r * HD + t];
            atomicAdd(&gcol[t], S);
        }
        if (t < 64) {
            int row = base + t;
            if (row < NN) {
                float S = 0.f;
#pragma unroll
                for (int g = 0; g < 16; ++g) S += rr[t * 16 + g];
                growss[row] = S;
            }
        }
    }
}

// ---------------- CSR build ----------------
__global__ void hist_kernel(const int* __restrict__ ei, int* __restrict__ cnt, int E) {
    int e = blockIdx.x * blockDim.x + threadIdx.x;
    if (e < E) atomicAdd(&cnt[ei[E + e]], 1);
}

// hierarchical exclusive scan of cnt[NN] -> rowptr[NN+1], cursor in-place in cnt
__global__ __launch_bounds__(256) void scan_part1(const int* __restrict__ cnt,
                                                  int* __restrict__ bsum) {
    __shared__ int sh[256];
    int i = blockIdx.x * 256 + threadIdx.x;
    int t = threadIdx.x;
    sh[t] = (i < NN) ? cnt[i] : 0;
    __syncthreads();
    for (int off = 128; off > 0; off >>= 1) {
        if (t < off) sh[t] += sh[t + off];
        __syncthreads();
    }
    if (t == 0) bsum[blockIdx.x] = sh[0];
}

__global__ __launch_bounds__(256) void scan_part2(int* __restrict__ bsum) {
    __shared__ int sh[256];
    int t = threadIdx.x;
    int v = (t < SCAN_NB) ? bsum[t] : 0;
    sh[t] = v;
    __syncthreads();
    for (int off = 1; off < 256; off <<= 1) {
        int u = sh[t];
        if (t >= off) u += sh[t - off];
        __syncthreads();
        sh[t] = u;
        __syncthreads();
    }
    if (t < SCAN_NB) bsum[t] = sh[t] - v;    // exclusive block offsets
}

__global__ __launch_bounds__(256) void scan_part3(int* __restrict__ cnt,
                                                  const int* __restrict__ bsum,
                                                  int* __restrict__ rowptr) {
    __shared__ int sh[256];
    int i = blockIdx.x * 256 + threadIdx.x;
    int t = threadIdx.x;
    int v = (i < NN) ? cnt[i] : 0;
    sh[t] = v;
    __syncthreads();
    for (int off = 1; off < 256; off <<= 1) {
        int u = sh[t];
        if (t >= off) u += sh[t - off];
        __syncthreads();
        sh[t] = u;
        __syncthreads();
    }
    int excl = sh[t] - v + bsum[blockIdx.x];
    if (i < NN) { rowptr[i] = excl; cnt[i] = excl; }   // cnt becomes fill cursor
    if (i == NN - 1) rowptr[NN] = excl + v;
}

__global__ void fill_kernel(const int* __restrict__ ei, int* __restrict__ cursor,
                            int* __restrict__ srcs, int E) {
    int e = blockIdx.x * blockDim.x + threadIdx.x;
    if (e >= E) return;
    int src = ei[e];
    int dst = ei[E + e];
    int slot = atomicAdd(&cursor[dst], 1);
    srcs[slot] = src;
}

// -------- gather: z[i] = h0[i] + sum_{e:dst=i} h0[src_e]  (float4, 4-way split) ----
__global__ __launch_bounds__(768) void gather_kernel(
    const float* __restrict__ h0, const int* __restrict__ rowptr,
    const int* __restrict__ srcs, float* __restrict__ z)
{
    __shared__ float4 red[768];
    const int tid = threadIdx.x;
    const int rl  = tid / 96;          // 0..7
    const int wi  = tid - rl * 96;
    const int g   = wi / 24;           // 0..3 edge group
    const int c   = wi - g * 24;       // 0..23 float4 lane
    const int row = blockIdx.x * 8 + rl;

    const int p0 = rowptr[row];
    const int cnt = rowptr[row + 1] - p0;
    int q0 = p0 + (cnt * g) / 4;
    int q1 = p0 + (cnt * (g + 1)) / 4;

    float4 acc = (g == 0) ? ld4(h0 + (size_t)row * HD + c * 4)
                          : make_float4(0.f, 0.f, 0.f, 0.f);
    int p = q0;
    for (; p + 4 <= q1; p += 4) {
        int s0 = srcs[p], s1 = srcs[p + 1], s2 = srcs[p + 2], s3 = srcs[p + 3];
        float4 v0 = ld4(h0 + (size_t)s0 * HD + c * 4);
        float4 v1 = ld4(h0 + (size_t)s1 * HD + c * 4);
        float4 v2 = ld4(h0 + (size_t)s2 * HD + c * 4);
        float4 v3 = ld4(h0 + (size_t)s3 * HD + c * 4);
        acc = add4(acc, add4(add4(v0, v1), add4(v2, v3)));
    }
    for (; p < q1; ++p)
        acc = add4(acc, ld4(h0 + (size_t)srcs[p] * HD + c * 4));

    red[tid] = acc;
    __syncthreads();
    if (g == 0) {
        acc = add4(add4(acc, red[tid + 24]), add4(red[tid + 48], red[tid + 72]));
        *(float4*)(z + (size_t)row * HD + c * 4) = acc;
    }
}

__global__ void bn_finalize_kernel(const float* __restrict__ sum, const float* __restrict__ sumsq,
                                   const float* __restrict__ gamma, const float* __restrict__ beta,
                                   float* __restrict__ scale, float* __restrict__ shift)
{
    int f = threadIdx.x;
    if (f < HD) {
        float mean = sum[f] * (1.0f / NN);
        float var  = fmaxf(sumsq[f] * (1.0f / NN) - mean * mean, 0.0f);
        float rstd = rsqrtf(var + BN_EPS);
        float sc = rstd * gamma[f];
        scale[f] = sc;
        shift[f] = beta[f] - mean * sc;
    }
}

// ---------------- PairNorm: streaming float4, in place ----------------
__global__ __launch_bounds__(256) void pn_kernel(float* l1, const float* __restrict__ colsum,
                                                 const float* __restrict__ rowss)
{
    int idx = blockIdx.x * 256 + threadIdx.x;   // float4 index
    if (idx >= NN * 24) return;
    int row = idx / 24;
    int q = idx - row * 24;
    float rs = rsqrtf(1e-6f + rowss[row]);
    float4 v = ld4(l1 + (size_t)idx * 4);
    float4 cm = ld4(colsum + q * 4);
    v.x = PN_SCALE * v.x * rs - cm.x * (1.0f / NN);
    v.y = PN_SCALE * v.y * rs - cm.y * (1.0f / NN);
    v.z = PN_SCALE * v.z * rs - cm.z * (1.0f / NN);
    v.w = PN_SCALE * v.w * rs - cm.w * (1.0f / NN);
    *(float4*)(l1 + (size_t)idx * 4) = v;
}

extern "C" void kernel_launch(void* const* d_in, const int* in_sizes, int n_in,
                              void* d_out, int out_size, void* d_ws, size_t ws_size,
                              hipStream_t stream) {
    const float* x     = (const float*)d_in[0];
    const int*   ei    = (const int*)d_in[1];
    const float* W0    = (const float*)d_in[2];
    const float* b0    = (const float*)d_in[3];
    const float* W1    = (const float*)d_in[4];
    const float* b1    = (const float*)d_in[5];
    const float* gamma = (const float*)d_in[6];
    const float* beta  = (const float*)d_in[7];
    const float* W2    = (const float*)d_in[8];
    const float* b2    = (const float*)d_in[9];

    float* out_l1 = (float*)d_out;                 // [N,96]: z -> h -> l1 (in place)
    float* out_h0 = out_l1 + (size_t)NN * HD;      // [N,96]: h0 output

    // ws (~3.8 MB): stats 1024 fl | rowss NN fl | cnt NN int | rowptr NN+2 int |
    //               bsum 256 int | srcs E int
    float* stats   = (float*)d_ws;
    float* s_sum   = stats;            // 96
    float* s_sumsq = stats + HD;       // 96
    float* s_col   = stats + 2 * HD;   // 96
    float* s_scale = stats + 288;      // 96
    float* s_shift = stats + 384;      // 96
    float* rowss = stats + 1024;
    int* cnt    = (int*)(rowss + NN);
    int* rowptr = cnt + NN;
    int* bsum   = rowptr + NN + 2;
    int* srcs   = bsum + 256;

    const int E = in_sizes[1] / 2;                 // 800000
    const int GB = (NN + 63) / 64;                 // 782

    zero_kernel<<<(1024 + NN + 255) / 256, 256, 0, stream>>>(stats, cnt);
    // 1) h0 = x @ W0^T + b0
    gemm_tiled<IN_DIM, 0><<<GB, 256, 0, stream>>>(x, W0, b0, out_h0, nullptr, nullptr,
                                                  nullptr, nullptr, nullptr, nullptr);
    // 2) CSR build: histogram -> hierarchical scan -> fill
    hist_kernel<<<(E + 255) / 256, 256, 0, stream>>>(ei, cnt, E);
    scan_part1<<<SCAN_NB, 256, 0, stream>>>(cnt, bsum);
    scan_part2<<<1, 256, 0, stream>>>(bsum);
    scan_part3<<<SCAN_NB, 256, 0, stream>>>(cnt, bsum, rowptr);
    fill_kernel<<<(E + 255) / 256, 256, 0, stream>>>(ei, cnt, srcs, E);
    // 3) gather: z = h0 + segment_sum(h0[src])
    gather_kernel<<<NN / 8, 768, 0, stream>>>(out_h0, rowptr, srcs, out_l1);
    // 4) h = z @ W1^T + b1 (in place) + fused BN stats
    gemm_tiled<HD, 1><<<GB, 256, 0, stream>>>(out_l1, W1, b1, out_l1, nullptr, nullptr,
                                              s_sum, s_sumsq, nullptr, nullptr);
    bn_finalize_kernel<<<1, 128, 0, stream>>>(s_sum, s_sumsq, gamma, beta, s_scale, s_shift);
    // 5) l1 = relu(bn(h)) @ W2^T + b2 (in place) + fused PN stats
    gemm_tiled<HD, 2><<<GB, 256, 0, stream>>>(out_l1, W2, b2, out_l1, s_scale, s_shift,
                                              nullptr, nullptr, s_col, rowss);
    // 6) PairNorm finalize (streaming, in place)
    pn_kernel<<<(NN * 24 + 255) / 256, 256, 0, stream>>>(out_l1, s_col, rowss);
}

// Round 9
// 355.384 us; speedup vs baseline: 2.0855x; 1.0149x over previous
//
#include <hip/hip_runtime.h>

#define NN 50000
#define IN_DIM 128
#define HD 96
#define BN_EPS 1e-5f
#define PN_SCALE 20.0f
#define SCAN_NB 196   // ceil(50000/256)

__device__ __forceinline__ float4 ld4(const float* p) { return *(const float4*)p; }
__device__ __forceinline__ float4 add4(float4 a, float4 b) {
    return make_float4(a.x + b.x, a.y + b.y, a.z + b.z, a.w + b.w);
}

// ---------------- zero stats + CSR counters ----------------
__global__ void zero_kernel(float* stats, int* cnt) {
    int i = blockIdx.x * blockDim.x + threadIdx.x;
    if (i < 1024) stats[i] = 0.0f;
    int j = i - 1024;
    if (j >= 0 && j < NN) cnt[j] = 0;
}

// ---------------- tiled GEMM: C[N,96] = act(A[N,K]) @ W[96,K]^T + b ----------
template<int K, int MODE>
__global__ __launch_bounds__(256) void gemm_tiled(
    const float* A, const float* __restrict__ W, const float* __restrict__ bias,
    float* out, const float* __restrict__ scale, const float* __restrict__ shift,
    float* __restrict__ gsum, float* __restrict__ gsumsq,
    float* __restrict__ gcol, float* __restrict__ growss)
{
    constexpr int CK = 32;
    __shared__ float sh[64 * (CK + 1) + HD * (CK + 1)];   // 5280 floats
    float* As = sh;
    float* Ws = sh + 64 * (CK + 1);

    const int t  = threadIdx.x;
    const int tx = t & 15;        // cols tx*6 .. tx*6+5
    const int ty = t >> 4;        // rows ty*4 .. ty*4+3
    const int base = blockIdx.x * 64;

    float acc[4][6];
#pragma unroll
    for (int i = 0; i < 4; ++i)
#pragma unroll
        for (int j = 0; j < 6; ++j) acc[i][j] = 0.0f;

    for (int kc = 0; kc < K; kc += CK) {
#pragma unroll
        for (int it = 0; it < 2; ++it) {
            int q = t + it * 256;
            int r = q >> 3, c4 = q & 7;
            int row = base + r;
            float4 v = make_float4(0.f, 0.f, 0.f, 0.f);
            if (row < NN) v = ld4(A + (size_t)row * K + kc + c4 * 4);
            if (MODE == 2) {
                float4 sc = ld4(scale + kc + c4 * 4);
                float4 shf = ld4(shift + kc + c4 * 4);
                v.x = fmaxf(v.x * sc.x + shf.x, 0.f);
                v.y = fmaxf(v.y * sc.y + shf.y, 0.f);
                v.z = fmaxf(v.z * sc.z + shf.z, 0.f);
                v.w = fmaxf(v.w * sc.w + shf.w, 0.f);
            }
            float* d = As + r * (CK + 1) + c4 * 4;
            d[0] = v.x; d[1] = v.y; d[2] = v.z; d[3] = v.w;
        }
#pragma unroll
        for (int it = 0; it < 3; ++it) {
            int q = t + it * 256;
            int r = q >> 3, c4 = q & 7;
            float4 v = ld4(W + (size_t)r * K + kc + c4 * 4);
            float* d = Ws + r * (CK + 1) + c4 * 4;
            d[0] = v.x; d[1] = v.y; d[2] = v.z; d[3] = v.w;
        }
        __syncthreads();
#pragma unroll
        for (int kk = 0; kk < CK; ++kk) {
            float a[4], b[6];
#pragma unroll
            for (int i = 0; i < 4; ++i) a[i] = As[(ty * 4 + i) * (CK + 1) + kk];
#pragma unroll
            for (int j = 0; j < 6; ++j) b[j] = Ws[(tx * 6 + j) * (CK + 1) + kk];
#pragma unroll
            for (int i = 0; i < 4; ++i)
#pragma unroll
                for (int j = 0; j < 6; ++j) acc[i][j] += a[i] * b[j];
        }
        __syncthreads();
    }

    float cv[4][6];
#pragma unroll
    for (int j = 0; j < 6; ++j) {
        float bs = bias[tx * 6 + j];
#pragma unroll
        for (int i = 0; i < 4; ++i) cv[i][j] = acc[i][j] + bs;
    }
#pragma unroll
    for (int i = 0; i < 4; ++i) {
        int row = base + ty * 4 + i;
        if (row < NN) {
#pragma unroll
            for (int j = 0; j < 6; ++j)
                out[(size_t)row * HD + tx * 6 + j] = cv[i][j];
        }
    }

    if (MODE == 1) {
        float* rs_sum = sh;            // [16][96]
        float* rs_sq  = sh + 1536;     // [16][96]
        __syncthreads();
#pragma unroll
        for (int j = 0; j < 6; ++j) {
            float s = 0.f, q = 0.f;
#pragma unroll
            for (int i = 0; i < 4; ++i) {
                int row = base + ty * 4 + i;
                float v = (row < NN) ? cv[i][j] : 0.f;
                s += v; q += v * v;
            }
            rs_sum[ty * HD + tx * 6 + j] = s;
            rs_sq[ty * HD + tx * 6 + j]  = q;
        }
        __syncthreads();
        if (t < HD) {
            float S = 0.f, Q = 0.f;
#pragma unroll
            for (int r = 0; r < 16; ++r) { S += rs_sum[r * HD + t]; Q += rs_sq[r * HD + t]; }
            atomicAdd(&gsum[t], S);
            atomicAdd(&gsumsq[t], Q);
        }
    }

    if (MODE == 2) {
        float* rs_sum = sh;            // [16][96]
        float* rr     = sh + 1536;     // [64][16]
        __syncthreads();
#pragma unroll
        for (int j = 0; j < 6; ++j) {
            float s = 0.f;
#pragma unroll
            for (int i = 0; i < 4; ++i) {
                int row = base + ty * 4 + i;
                s += (row < NN) ? cv[i][j] : 0.f;
            }
            rs_sum[ty * HD + tx * 6 + j] = s;
        }
#pragma unroll
        for (int i = 0; i < 4; ++i) {
            float q = 0.f;
#pragma unroll
            for (int j = 0; j < 6; ++j) q += cv[i][j] * cv[i][j];
            rr[(ty * 4 + i) * 16 + tx] = q;
        }
        __syncthreads();
        if (t < HD) {
            float S = 0.f;
#pragma unroll
            for (int r = 0; r < 16; ++r) S += rs_sum[r * HD + t];
            atomicAdd(&gcol[t], S);
        }
        if (t < 64) {
            int row = base + t;
            if (row < NN) {
                float S = 0.f;
#pragma unroll
                for (int g = 0; g < 16; ++g) S += rr[t * 16 + g];
                growss[row] = S;
            }
        }
    }
}

// ---------------- CSR build ----------------
__global__ void hist_kernel(const int* __restrict__ ei, int* __restrict__ cnt, int E) {
    int e = blockIdx.x * blockDim.x + threadIdx.x;
    if (e < E) atomicAdd(&cnt[ei[E + e]], 1);
}

__global__ __launch_bounds__(256) void scan_part1(const int* __restrict__ cnt,
                                                  int* __restrict__ bsum) {
    __shared__ int sh[256];
    int i = blockIdx.x * 256 + threadIdx.x;
    int t = threadIdx.x;
    sh[t] = (i < NN) ? cnt[i] : 0;
    __syncthreads();
    for (int off = 128; off > 0; off >>= 1) {
        if (t < off) sh[t] += sh[t + off];
        __syncthreads();
    }
    if (t == 0) bsum[blockIdx.x] = sh[0];
}

__global__ __launch_bounds__(256) void scan_part2(int* __restrict__ bsum) {
    __shared__ int sh[256];
    int t = threadIdx.x;
    int v = (t < SCAN_NB) ? bsum[t] : 0;
    sh[t] = v;
    __syncthreads();
    for (int off = 1; off < 256; off <<= 1) {
        int u = sh[t];
        if (t >= off) u += sh[t - off];
        __syncthreads();
        sh[t] = u;
        __syncthreads();
    }
    if (t < SCAN_NB) bsum[t] = sh[t] - v;    // exclusive block offsets
}

__global__ __launch_bounds__(256) void scan_part3(int* __restrict__ cnt,
                                                  const int* __restrict__ bsum,
                                                  int* __restrict__ rowptr) {
    __shared__ int sh[256];
    int i = blockIdx.x * 256 + threadIdx.x;
    int t = threadIdx.x;
    int v = (i < NN) ? cnt[i] : 0;
    sh[t] = v;
    __syncthreads();
    for (int off = 1; off < 256; off <<= 1) {
        int u = sh[t];
        if (t >= off) u += sh[t - off];
        __syncthreads();
        sh[t] = u;
        __syncthreads();
    }
    int excl = sh[t] - v + bsum[blockIdx.x];
    if (i < NN) { rowptr[i] = excl; cnt[i] = excl; }   // cnt becomes fill cursor
    if (i == NN - 1) rowptr[NN] = excl + v;
}

// fill with dst-range multipass: clusters slot-writes of a row in time so the
// srcs write window per pass (~460 KB) stays L2-resident -> line coalescing.
// Each thread register-caches 4 edges; 7 passes over dst>>13 = 0..6.
__global__ __launch_bounds__(256) void fill_kernel(const int* __restrict__ ei,
                                                   int* __restrict__ cursor,
                                                   int* __restrict__ srcs, int E) {
    int t4 = blockIdx.x * 256 + threadIdx.x;
    int e0 = t4 * 4;
    int src[4], dst[4];
#pragma unroll
    for (int i = 0; i < 4; ++i) {
        int e = e0 + i;
        bool ok = e < E;
        dst[i] = ok ? ei[E + e] : -1;
        src[i] = ok ? ei[e] : 0;
    }
    for (int pass = 0; pass < 7; ++pass) {
#pragma unroll
        for (int i = 0; i < 4; ++i) {
            if (dst[i] >= 0 && (dst[i] >> 13) == pass) {
                int slot = atomicAdd(&cursor[dst[i]], 1);
                srcs[slot] = src[i];
            }
        }
    }
}

// -------- gather: z[i] = h0[i] + sum_{e:dst=i} h0[src_e]  (float4, 4-way split) ----
__global__ __launch_bounds__(768) void gather_kernel(
    const float* __restrict__ h0, const int* __restrict__ rowptr,
    const int* __restrict__ srcs, float* __restrict__ z)
{
    __shared__ float4 red[768];
    const int tid = threadIdx.x;
    const int rl  = tid / 96;          // 0..7
    const int wi  = tid - rl * 96;
    const int g   = wi / 24;           // 0..3 edge group
    const int c   = wi - g * 24;       // 0..23 float4 lane
    const int row = blockIdx.x * 8 + rl;

    const int p0 = rowptr[row];
    const int cnt = rowptr[row + 1] - p0;
    int q0 = p0 + (cnt * g) / 4;
    int q1 = p0 + (cnt * (g + 1)) / 4;

    float4 acc = (g == 0) ? ld4(h0 + (size_t)row * HD + c * 4)
                          : make_float4(0.f, 0.f, 0.f, 0.f);
    int p = q0;
    for (; p + 4 <= q1; p += 4) {
        int s0 = srcs[p], s1 = srcs[p + 1], s2 = srcs[p + 2], s3 = srcs[p + 3];
        float4 v0 = ld4(h0 + (size_t)s0 * HD + c * 4);
        float4 v1 = ld4(h0 + (size_t)s1 * HD + c * 4);
        float4 v2 = ld4(h0 + (size_t)s2 * HD + c * 4);
        float4 v3 = ld4(h0 + (size_t)s3 * HD + c * 4);
        acc = add4(acc, add4(add4(v0, v1), add4(v2, v3)));
    }
    for (; p < q1; ++p)
        acc = add4(acc, ld4(h0 + (size_t)srcs[p] * HD + c * 4));

    red[tid] = acc;
    __syncthreads();
    if (g == 0) {
        acc = add4(add4(acc, red[tid + 24]), add4(red[tid + 48], red[tid + 72]));
        *(float4*)(z + (size_t)row * HD + c * 4) = acc;
    }
}

__global__ void bn_finalize_kernel(const float* __restrict__ sum, const float* __restrict__ sumsq,
                                   const float* __restrict__ gamma, const float* __restrict__ beta,
                                   float* __restrict__ scale, float* __restrict__ shift)
{
    int f = threadIdx.x;
    if (f < HD) {
        float mean = sum[f] * (1.0f / NN);
        float var  = fmaxf(sumsq[f] * (1.0f / NN) - mean * mean, 0.0f);
        float rstd = rsqrtf(var + BN_EPS);
        float sc = rstd * gamma[f];
        scale[f] = sc;
        shift[f] = beta[f] - mean * sc;
    }
}

// ---------------- PairNorm: streaming float4, in place ----------------
__global__ __launch_bounds__(256) void pn_kernel(float* l1, const float* __restrict__ colsum,
                                                 const float* __restrict__ rowss)
{
    int idx = blockIdx.x * 256 + threadIdx.x;   // float4 index
    if (idx >= NN * 24) return;
    int row = idx / 24;
    int q = idx - row * 24;
    float rs = rsqrtf(1e-6f + rowss[row]);
    float4 v = ld4(l1 + (size_t)idx * 4);
    float4 cm = ld4(colsum + q * 4);
    v.x = PN_SCALE * v.x * rs - cm.x * (1.0f / NN);
    v.y = PN_SCALE * v.y * rs - cm.y * (1.0f / NN);
    v.z = PN_SCALE * v.z * rs - cm.z * (1.0f / NN);
    v.w = PN_SCALE * v.w * rs - cm.w * (1.0f / NN);
    *(float4*)(l1 + (size_t)idx * 4) = v;
}

extern "C" void kernel_launch(void* const* d_in, const int* in_sizes, int n_in,
                              void* d_out, int out_size, void* d_ws, size_t ws_size,
                              hipStream_t stream) {
    const float* x     = (const float*)d_in[0];
    const int*   ei    = (const int*)d_in[1];
    const float* W0    = (const float*)d_in[2];
    const float* b0    = (const float*)d_in[3];
    const float* W1    = (const float*)d_in[4];
    const float* b1    = (const float*)d_in[5];
    const float* gamma = (const float*)d_in[6];
    const float* beta  = (const float*)d_in[7];
    const float* W2    = (const float*)d_in[8];
    const float* b2    = (const float*)d_in[9];

    float* out_l1 = (float*)d_out;                 // [N,96]: z -> h -> l1 (in place)
    float* out_h0 = out_l1 + (size_t)NN * HD;      // [N,96]: h0 output

    float* stats   = (float*)d_ws;
    float* s_sum   = stats;            // 96
    float* s_sumsq = stats + HD;       // 96
    float* s_col   = stats + 2 * HD;   // 96
    float* s_scale = stats + 288;      // 96
    float* s_shift = stats + 384;      // 96
    float* rowss = stats + 1024;
    int* cnt    = (int*)(rowss + NN);
    int* rowptr = cnt + NN;
    int* bsum   = rowptr + NN + 2;
    int* srcs   = bsum + 256;

    const int E = in_sizes[1] / 2;                 // 800000
    const int GB = (NN + 63) / 64;                 // 782

    zero_kernel<<<(1024 + NN + 255) / 256, 256, 0, stream>>>(stats, cnt);
    // 1) h0 = x @ W0^T + b0
    gemm_tiled<IN_DIM, 0><<<GB, 256, 0, stream>>>(x, W0, b0, out_h0, nullptr, nullptr,
                                                  nullptr, nullptr, nullptr, nullptr);
    // 2) CSR build: histogram -> hierarchical scan -> multipass fill
    hist_kernel<<<(E + 255) / 256, 256, 0, stream>>>(ei, cnt, E);
    scan_part1<<<SCAN_NB, 256, 0, stream>>>(cnt, bsum);
    scan_part2<<<1, 256, 0, stream>>>(bsum);
    scan_part3<<<SCAN_NB, 256, 0, stream>>>(cnt, bsum, rowptr);
    fill_kernel<<<(E / 4 + 255) / 256, 256, 0, stream>>>(ei, cnt, srcs, E);
    // 3) gather: z = h0 + segment_sum(h0[src])
    gather_kernel<<<NN / 8, 768, 0, stream>>>(out_h0, rowptr, srcs, out_l1);
    // 4) h = z @ W1^T + b1 (in place) + fused BN stats
    gemm_tiled<HD, 1><<<GB, 256, 0, stream>>>(out_l1, W1, b1, out_l1, nullptr, nullptr,
                                              s_sum, s_sumsq, nullptr, nullptr);
    bn_finalize_kernel<<<1, 128, 0, stream>>>(s_sum, s_sumsq, gamma, beta, s_scale, s_shift);
    // 5) l1 = relu(bn(h)) @ W2^T + b2 (in place) + fused PN stats
    gemm_tiled<HD, 2><<<GB, 256, 0, stream>>>(out_l1, W2, b2, out_l1, s_scale, s_shift,
                                              nullptr, nullptr, s_col, rowss);
    // 6) PairNorm finalize (streaming, in place)
    pn_kernel<<<(NN * 24 + 255) / 256, 256, 0, stream>>>(out_l1, s_col, rowss);
}